// Round 1
// baseline (555.655 us; speedup 1.0000x reference)
//
#include <hip/hip_runtime.h>
#include <hip/hip_bf16.h>

#define N_NODES 50000
#define N_EDGES 800000
#define DIM_IN 64
#define DIM_H 32
#define HEADS 4
#define NCLS 10
#define NEG 0.2f

// ---------------- CSR build ----------------

__global__ void k_hist(const int* __restrict__ dst, int* __restrict__ deg) {
    int e = blockIdx.x * 256 + threadIdx.x;
    if (e < N_EDGES) atomicAdd(&deg[dst[e]], 1);
}

__global__ void k_scan_block(const int* __restrict__ deg, int* __restrict__ row,
                             int* __restrict__ bsums) {
    __shared__ int s[256];
    int i = blockIdx.x * 256 + threadIdx.x;
    int v = (i < N_NODES) ? deg[i] : 0;
    s[threadIdx.x] = v;
    __syncthreads();
    for (int off = 1; off < 256; off <<= 1) {
        int t = (threadIdx.x >= off) ? s[threadIdx.x - off] : 0;
        __syncthreads();
        s[threadIdx.x] += t;
        __syncthreads();
    }
    if (i < N_NODES) row[i] = s[threadIdx.x] - v;  // exclusive
    if (threadIdx.x == 255) bsums[blockIdx.x] = s[255];
}

__global__ void k_scan_sums(int* __restrict__ bsums, int nb) {
    __shared__ int s[256];
    int v = (threadIdx.x < nb) ? bsums[threadIdx.x] : 0;
    s[threadIdx.x] = v;
    __syncthreads();
    for (int off = 1; off < 256; off <<= 1) {
        int t = (threadIdx.x >= off) ? s[threadIdx.x - off] : 0;
        __syncthreads();
        s[threadIdx.x] += t;
        __syncthreads();
    }
    if (threadIdx.x < nb) bsums[threadIdx.x] = s[threadIdx.x] - v;  // exclusive
}

__global__ void k_scan_add(int* __restrict__ row, int* __restrict__ cursor,
                           const int* __restrict__ bsums) {
    int i = blockIdx.x * 256 + threadIdx.x;
    if (i < N_NODES) {
        int r = row[i] + bsums[blockIdx.x];
        row[i] = r;
        cursor[i] = r;
    }
    if (i == 0) row[N_NODES] = N_EDGES;
}

__global__ void k_scatter(const int* __restrict__ dst, int* __restrict__ cursor,
                          int* __restrict__ eidx) {
    int e = blockIdx.x * 256 + threadIdx.x;
    if (e < N_EDGES) {
        int d = dst[e];
        int p = atomicAdd(&cursor[d], 1);
        eidx[p] = e;
    }
}

// ---------------- dense ----------------

// x[n][j] = g_feats[n] . W_in[:,j] + b_in[j]
__global__ void k_embed(const float* __restrict__ gf, const float* __restrict__ W,
                        const float* __restrict__ b, float* __restrict__ x) {
    __shared__ float Ws[DIM_IN * DIM_H];
    for (int t = threadIdx.x; t < DIM_IN * DIM_H; t += 256) Ws[t] = W[t];
    __syncthreads();
    int t = blockIdx.x * 256 + threadIdx.x;
    int n = t >> 5, j = t & 31;
    if (n >= N_NODES) return;
    const float* gr = gf + (size_t)n * DIM_IN;
    float sum = b[j];
#pragma unroll
    for (int k = 0; k < DIM_IN; k++) sum += gr[k] * Ws[k * DIM_H + j];
    x[(size_t)n * DIM_H + j] = sum;
}

// fs/fd[n][j] = x[n] . W[:,j] + b[j], j in [0,128)
__global__ void k_proj(const float* __restrict__ x, const float* __restrict__ Wsrc,
                       const float* __restrict__ bsrc, const float* __restrict__ Wdst,
                       const float* __restrict__ bdst, float* __restrict__ fs,
                       float* __restrict__ fd) {
    __shared__ float Ws[DIM_H * 128];
    __shared__ float Wd[DIM_H * 128];
    for (int t = threadIdx.x; t < DIM_H * 128; t += 256) {
        Ws[t] = Wsrc[t];
        Wd[t] = Wdst[t];
    }
    __syncthreads();
    int t = blockIdx.x * 256 + threadIdx.x;
    int n = t >> 7, j = t & 127;
    if (n >= N_NODES) return;
    const float* xr = x + (size_t)n * DIM_H;
    float ss = bsrc[j], sd = bdst[j];
#pragma unroll
    for (int k = 0; k < DIM_H; k++) {
        float xv = xr[k];
        ss += xv * Ws[k * 128 + j];
        sd += xv * Wd[k * 128 + j];
    }
    fs[(size_t)n * 128 + j] = ss;
    fd[(size_t)n * 128 + j] = sd;
}

// ---------------- GAT gather (per-node softmax + aggregate) ----------------
// One wave per destination node. lane l: head h = l>>4, float2 slot = l (fs row
// viewed as float2[64]). Softmax shift dropped (shift-invariant, |s| small).
// Output overwrites fd[n] (safe: only own row read).
__global__ void k_gather(const float* __restrict__ fs, float* __restrict__ fd,
                         const float* __restrict__ attn, const int* __restrict__ row,
                         const int* __restrict__ eidx, const int* __restrict__ src) {
    int wave = threadIdx.x >> 6;
    int lane = threadIdx.x & 63;
    int n = blockIdx.x * 4 + wave;
    if (n >= N_NODES) return;
    float2 a2 = ((const float2*)attn)[lane];
    float2 fdv = ((const float2*)(fd + (size_t)n * 128))[lane];
    float2 acc = {0.f, 0.f};
    float den = 0.f;
    int beg = row[n], end = row[n + 1];
    for (int i = beg; i < end; ++i) {
        int e = eidx[i];
        int s = src[e];
        float2 f = ((const float2*)(fs + (size_t)s * 128))[lane];
        float tx = f.x + fdv.x; tx = tx > 0.f ? tx : NEG * tx;
        float ty = f.y + fdv.y; ty = ty > 0.f ? ty : NEG * ty;
        float p = tx * a2.x + ty * a2.y;
        // reduce over the 16 lanes of this head
        p += __shfl_xor(p, 1, 64);
        p += __shfl_xor(p, 2, 64);
        p += __shfl_xor(p, 4, 64);
        p += __shfl_xor(p, 8, 64);
        float w = __expf(p);
        den += w;
        acc.x += w * f.x;
        acc.y += w * f.y;
    }
    float inv = den > 0.f ? 1.f / den : 0.f;
    float2 o = {acc.x * inv, acc.y * inv};
    ((float2*)(fd + (size_t)n * 128))[lane] = o;
}

// h[n][d] = relu(mean over heads)
__global__ void k_head_mean(const float* __restrict__ ob, float* __restrict__ x) {
    int t = blockIdx.x * 256 + threadIdx.x;
    int n = t >> 5, d = t & 31;
    if (n >= N_NODES) return;
    const float* r = ob + (size_t)n * 128;
    float v = (r[d] + r[32 + d] + r[64 + d] + r[96 + d]) * 0.25f;
    x[(size_t)n * 32 + d] = v > 0.f ? v : 0.f;
}

// partial[b][d] = sum over this block's nodes of sum over heads
__global__ void k_reduce(const float* __restrict__ ob, float* __restrict__ partial) {
    int d = threadIdx.x & 31, g = threadIdx.x >> 5;
    float acc = 0.f;
    int stride = gridDim.x * 8;
    for (int n = blockIdx.x * 8 + g; n < N_NODES; n += stride) {
        const float* r = ob + (size_t)n * 128;
        acc += r[d] + r[32 + d] + r[64 + d] + r[96 + d];
    }
    __shared__ float s[256];
    s[threadIdx.x] = acc;
    __syncthreads();
    for (int off = 128; off >= 32; off >>= 1) {
        if (threadIdx.x < off) s[threadIdx.x] += s[threadIdx.x + off];
        __syncthreads();
    }
    if (threadIdx.x < 32) partial[blockIdx.x * 32 + threadIdx.x] = s[threadIdx.x];
}

__global__ void k_final(const float* __restrict__ partial, const float* __restrict__ Wh1,
                        const float* __restrict__ bh1, const float* __restrict__ Wh2,
                        const float* __restrict__ bh2, float* __restrict__ out) {
    __shared__ float gv[32], gh[32], lg[16];
    int t = threadIdx.x;
    if (t < 32) {
        float s = 0.f;
        for (int b = 0; b < 256; b++) s += partial[b * 32 + t];
        gv[t] = s * (1.f / (4.f * (float)N_NODES));
    }
    __syncthreads();
    if (t < 32) {
        float s = bh1[t];
        for (int d = 0; d < 32; d++) s += gv[d] * Wh1[d * 32 + t];
        gh[t] = s > 0.f ? s : 0.f;
    }
    __syncthreads();
    if (t < NCLS) {
        float s = bh2[t];
        for (int j = 0; j < 32; j++) s += gh[j] * Wh2[j * NCLS + t];
        lg[t] = s;
    }
    __syncthreads();
    if (t == 0) {
        float m = lg[0];
        for (int c = 1; c < NCLS; c++) m = fmaxf(m, lg[c]);
        float ex[NCLS], sum = 0.f;
        for (int c = 0; c < NCLS; c++) {
            ex[c] = __expf(lg[c] - m);
            sum += ex[c];
        }
        float inv = 1.f / sum;
        for (int c = 0; c < NCLS; c++) out[c] = ex[c] * inv;
    }
}

extern "C" void kernel_launch(void* const* d_in, const int* in_sizes, int n_in,
                              void* d_out, int out_size, void* d_ws, size_t ws_size,
                              hipStream_t stream) {
    // setup_inputs() dict order:
    const float* g_feats = (const float*)d_in[0];
    const int* edge_src = (const int*)d_in[1];
    const int* edge_dst = (const int*)d_in[2];
    const float* W_in = (const float*)d_in[3];
    const float* b_in = (const float*)d_in[4];
    const float* W1_src = (const float*)d_in[5];
    const float* b1_src = (const float*)d_in[6];
    const float* W1_dst = (const float*)d_in[7];
    const float* b1_dst = (const float*)d_in[8];
    const float* attn1 = (const float*)d_in[9];
    const float* W2_src = (const float*)d_in[10];
    const float* b2_src = (const float*)d_in[11];
    const float* W2_dst = (const float*)d_in[12];
    const float* b2_dst = (const float*)d_in[13];
    const float* attn2 = (const float*)d_in[14];
    const float* Wh1 = (const float*)d_in[15];
    const float* bh1 = (const float*)d_in[16];
    const float* Wh2 = (const float*)d_in[17];
    const float* bh2 = (const float*)d_in[18];

    // workspace layout
    float* x = (float*)d_ws;                    // N*32
    float* fs = x + (size_t)N_NODES * 32;       // N*128
    float* fd = fs + (size_t)N_NODES * 128;     // N*128 (also layer output)
    float* partial = fd + (size_t)N_NODES * 128;  // 256*32
    int* deg = (int*)(partial + 256 * 32);      // N
    int* row = deg + N_NODES;                   // N+1
    int* cursor = row + N_NODES + 1;            // N
    int* eidx = cursor + N_NODES;               // E
    // (end ~61.5 MB)

    const int EB = (N_EDGES + 255) / 256;
    const int NB = (N_NODES + 255) / 256;  // 196
    int* bsums = eidx + N_EDGES;           // NB

    hipMemsetAsync(deg, 0, N_NODES * sizeof(int), stream);
    k_hist<<<EB, 256, 0, stream>>>(edge_dst, deg);
    k_scan_block<<<NB, 256, 0, stream>>>(deg, row, bsums);
    k_scan_sums<<<1, 256, 0, stream>>>(bsums, NB);
    k_scan_add<<<NB, 256, 0, stream>>>(row, cursor, bsums);
    k_scatter<<<EB, 256, 0, stream>>>(edge_dst, cursor, eidx);

    k_embed<<<(N_NODES * 32 + 255) / 256, 256, 0, stream>>>(g_feats, W_in, b_in, x);

    // layer 1
    k_proj<<<(N_NODES * 128 + 255) / 256, 256, 0, stream>>>(x, W1_src, b1_src, W1_dst,
                                                            b1_dst, fs, fd);
    k_gather<<<(N_NODES + 3) / 4, 256, 0, stream>>>(fs, fd, attn1, row, eidx, edge_src);
    k_head_mean<<<(N_NODES * 32 + 255) / 256, 256, 0, stream>>>(fd, x);

    // layer 2
    k_proj<<<(N_NODES * 128 + 255) / 256, 256, 0, stream>>>(x, W2_src, b2_src, W2_dst,
                                                            b2_dst, fs, fd);
    k_gather<<<(N_NODES + 3) / 4, 256, 0, stream>>>(fs, fd, attn2, row, eidx, edge_src);

    k_reduce<<<256, 256, 0, stream>>>(fd, partial);
    k_final<<<1, 256, 0, stream>>>(partial, Wh1, bh1, Wh2, bh2, (float*)d_out);
}

// Round 2
// 384.525 us; speedup vs baseline: 1.4450x; 1.4450x over previous
//
#include <hip/hip_runtime.h>
#include <hip/hip_bf16.h>

#define N_NODES 50000
#define N_EDGES 800000
#define DIM_IN 64
#define DIM_H 32
#define HEADS 4
#define NCLS 10
#define NEG 0.2f

// ---------------- CSR build ----------------

__global__ void k_hist(const int* __restrict__ dst, int* __restrict__ deg) {
    int e = blockIdx.x * 256 + threadIdx.x;
    if (e < N_EDGES) atomicAdd(&deg[dst[e]], 1);
}

__global__ void k_scan_block(const int* __restrict__ deg, int* __restrict__ row,
                             int* __restrict__ bsums) {
    __shared__ int s[256];
    int i = blockIdx.x * 256 + threadIdx.x;
    int v = (i < N_NODES) ? deg[i] : 0;
    s[threadIdx.x] = v;
    __syncthreads();
    for (int off = 1; off < 256; off <<= 1) {
        int t = (threadIdx.x >= off) ? s[threadIdx.x - off] : 0;
        __syncthreads();
        s[threadIdx.x] += t;
        __syncthreads();
    }
    if (i < N_NODES) row[i] = s[threadIdx.x] - v;  // exclusive
    if (threadIdx.x == 255) bsums[blockIdx.x] = s[255];
}

__global__ void k_scan_sums(int* __restrict__ bsums, int nb) {
    __shared__ int s[256];
    int v = (threadIdx.x < nb) ? bsums[threadIdx.x] : 0;
    s[threadIdx.x] = v;
    __syncthreads();
    for (int off = 1; off < 256; off <<= 1) {
        int t = (threadIdx.x >= off) ? s[threadIdx.x - off] : 0;
        __syncthreads();
        s[threadIdx.x] += t;
        __syncthreads();
    }
    if (threadIdx.x < nb) bsums[threadIdx.x] = s[threadIdx.x] - v;  // exclusive
}

__global__ void k_scan_add(int* __restrict__ row, int* __restrict__ cursor,
                           const int* __restrict__ bsums) {
    int i = blockIdx.x * 256 + threadIdx.x;
    if (i < N_NODES) {
        int r = row[i] + bsums[blockIdx.x];
        row[i] = r;
        cursor[i] = r;
    }
    if (i == 0) row[N_NODES] = N_EDGES;
}

// store SRC VALUES directly into adjacency (no eidx indirection)
__global__ void k_scatter(const int* __restrict__ dst, const int* __restrict__ srcarr,
                          int* __restrict__ cursor, int* __restrict__ adj) {
    int e = blockIdx.x * 256 + threadIdx.x;
    if (e < N_EDGES) {
        int d = dst[e];
        int s = srcarr[e];
        int p = atomicAdd(&cursor[d], 1);
        adj[p] = s;
    }
}

// ---------------- dense ----------------

__global__ void k_embed(const float* __restrict__ gf, const float* __restrict__ W,
                        const float* __restrict__ b, float* __restrict__ x) {
    __shared__ float Ws[DIM_IN * DIM_H];
    for (int t = threadIdx.x; t < DIM_IN * DIM_H; t += 256) Ws[t] = W[t];
    __syncthreads();
    int t = blockIdx.x * 256 + threadIdx.x;
    int n = t >> 5, j = t & 31;
    if (n >= N_NODES) return;
    const float* gr = gf + (size_t)n * DIM_IN;
    float sum = b[j];
#pragma unroll
    for (int k = 0; k < DIM_IN; k++) sum += gr[k] * Ws[k * DIM_H + j];
    x[(size_t)n * DIM_H + j] = sum;
}

__global__ void k_proj(const float* __restrict__ x, const float* __restrict__ Wsrc,
                       const float* __restrict__ bsrc, const float* __restrict__ Wdst,
                       const float* __restrict__ bdst, float* __restrict__ fs,
                       float* __restrict__ fd) {
    __shared__ float Ws[DIM_H * 128];
    __shared__ float Wd[DIM_H * 128];
    for (int t = threadIdx.x; t < DIM_H * 128; t += 256) {
        Ws[t] = Wsrc[t];
        Wd[t] = Wdst[t];
    }
    __syncthreads();
    int t = blockIdx.x * 256 + threadIdx.x;
    int n = t >> 7, j = t & 127;
    if (n >= N_NODES) return;
    const float* xr = x + (size_t)n * DIM_H;
    float ss = bsrc[j], sd = bdst[j];
#pragma unroll
    for (int k = 0; k < DIM_H; k++) {
        float xv = xr[k];
        ss += xv * Ws[k * 128 + j];
        sd += xv * Wd[k * 128 + j];
    }
    fs[(size_t)n * 128 + j] = ss;
    fd[(size_t)n * 128 + j] = sd;
}

// ---------------- GAT gather ----------------
// One wave per destination node. Lane l: head h=l>>4, float2 slot l of the
// 128-float row. Adjacency loaded lane-parallel (one coalesced load per <=64
// edges) and broadcast via shfl; 8 independent fs-row loads in flight per
// group to break the latency chain. Softmax shift dropped (shift-invariant;
// |logits| small). Epilogue fuses head-mean (+optional relu): the 4 heads of
// a given d live at lanes l, l^16, l^32, l^48.
__device__ __forceinline__ void edge_acc(float2 f, float2 fdv, float2 a2,
                                         float2& acc, float& den) {
    float tx = f.x + fdv.x; tx = tx > 0.f ? tx : NEG * tx;
    float ty = f.y + fdv.y; ty = ty > 0.f ? ty : NEG * ty;
    float p = tx * a2.x + ty * a2.y;
    p += __shfl_xor(p, 1, 64);
    p += __shfl_xor(p, 2, 64);
    p += __shfl_xor(p, 4, 64);
    p += __shfl_xor(p, 8, 64);
    float w = __expf(p);
    den += w;
    acc.x += w * f.x;
    acc.y += w * f.y;
}

__global__ void k_gather(const float* __restrict__ fs, const float* __restrict__ fd,
                         const float* __restrict__ attn, const int* __restrict__ row,
                         const int* __restrict__ adj, float* __restrict__ xout,
                         int do_relu) {
    int wave = threadIdx.x >> 6;
    int lane = threadIdx.x & 63;
    int n = blockIdx.x * 4 + wave;
    if (n >= N_NODES) return;
    float2 a2 = ((const float2*)attn)[lane];
    float2 fdv = ((const float2*)(fd + (size_t)n * 128))[lane];
    const float2* fs2 = (const float2*)fs;
    float2 acc = {0.f, 0.f};
    float den = 0.f;
    int beg = row[n], end = row[n + 1];
    for (int base = beg; base < end; base += 64) {
        int m = end - base;
        if (m > 64) m = 64;
        int myadj = (lane < m) ? adj[base + lane] : 0;
        int j = 0;
        for (; j + 8 <= m; j += 8) {
            int s0 = __shfl(myadj, j + 0, 64);
            int s1 = __shfl(myadj, j + 1, 64);
            int s2 = __shfl(myadj, j + 2, 64);
            int s3 = __shfl(myadj, j + 3, 64);
            int s4 = __shfl(myadj, j + 4, 64);
            int s5 = __shfl(myadj, j + 5, 64);
            int s6 = __shfl(myadj, j + 6, 64);
            int s7 = __shfl(myadj, j + 7, 64);
            float2 f0 = fs2[(size_t)s0 * 64 + lane];
            float2 f1 = fs2[(size_t)s1 * 64 + lane];
            float2 f2 = fs2[(size_t)s2 * 64 + lane];
            float2 f3 = fs2[(size_t)s3 * 64 + lane];
            float2 f4 = fs2[(size_t)s4 * 64 + lane];
            float2 f5 = fs2[(size_t)s5 * 64 + lane];
            float2 f6 = fs2[(size_t)s6 * 64 + lane];
            float2 f7 = fs2[(size_t)s7 * 64 + lane];
            edge_acc(f0, fdv, a2, acc, den);
            edge_acc(f1, fdv, a2, acc, den);
            edge_acc(f2, fdv, a2, acc, den);
            edge_acc(f3, fdv, a2, acc, den);
            edge_acc(f4, fdv, a2, acc, den);
            edge_acc(f5, fdv, a2, acc, den);
            edge_acc(f6, fdv, a2, acc, den);
            edge_acc(f7, fdv, a2, acc, den);
        }
        for (; j < m; ++j) {
            int s = __shfl(myadj, j, 64);
            float2 f = fs2[(size_t)s * 64 + lane];
            edge_acc(f, fdv, a2, acc, den);
        }
    }
    float inv = den > 0.f ? 1.f / den : 0.f;
    float ox = acc.x * inv, oy = acc.y * inv;
    // mean over heads: lanes l, l^16, l^32, l^48 hold the same d-pair
    float vx = ox + __shfl_xor(ox, 16, 64);
    float vy = oy + __shfl_xor(oy, 16, 64);
    vx += __shfl_xor(vx, 32, 64);
    vy += __shfl_xor(vy, 32, 64);
    vx *= 0.25f;
    vy *= 0.25f;
    if (do_relu) {
        vx = vx > 0.f ? vx : 0.f;
        vy = vy > 0.f ? vy : 0.f;
    }
    if (lane < 16) ((float2*)(xout + (size_t)n * 32))[lane] = make_float2(vx, vy);
}

// sum x[n][32] over nodes -> partial[block][32]
__global__ void k_reduce(const float* __restrict__ x, float* __restrict__ partial) {
    int d = threadIdx.x & 31, g = threadIdx.x >> 5;
    float acc = 0.f;
    int stride = gridDim.x * 8;
    for (int n = blockIdx.x * 8 + g; n < N_NODES; n += stride) {
        acc += x[(size_t)n * 32 + d];
    }
    __shared__ float s[256];
    s[threadIdx.x] = acc;
    __syncthreads();
    for (int off = 128; off >= 32; off >>= 1) {
        if (threadIdx.x < off) s[threadIdx.x] += s[threadIdx.x + off];
        __syncthreads();
    }
    if (threadIdx.x < 32) partial[blockIdx.x * 32 + threadIdx.x] = s[threadIdx.x];
}

__global__ void k_final(const float* __restrict__ partial, const float* __restrict__ Wh1,
                        const float* __restrict__ bh1, const float* __restrict__ Wh2,
                        const float* __restrict__ bh2, float* __restrict__ out) {
    __shared__ float gv[32], gh[32], lg[16];
    int t = threadIdx.x;
    if (t < 32) {
        float s = 0.f;
        for (int b = 0; b < 256; b++) s += partial[b * 32 + t];
        gv[t] = s * (1.f / (float)N_NODES);
    }
    __syncthreads();
    if (t < 32) {
        float s = bh1[t];
        for (int d = 0; d < 32; d++) s += gv[d] * Wh1[d * 32 + t];
        gh[t] = s > 0.f ? s : 0.f;
    }
    __syncthreads();
    if (t < NCLS) {
        float s = bh2[t];
        for (int j = 0; j < 32; j++) s += gh[j] * Wh2[j * NCLS + t];
        lg[t] = s;
    }
    __syncthreads();
    if (t == 0) {
        float m = lg[0];
        for (int c = 1; c < NCLS; c++) m = fmaxf(m, lg[c]);
        float ex[NCLS], sum = 0.f;
        for (int c = 0; c < NCLS; c++) {
            ex[c] = __expf(lg[c] - m);
            sum += ex[c];
        }
        float inv = 1.f / sum;
        for (int c = 0; c < NCLS; c++) out[c] = ex[c] * inv;
    }
}

extern "C" void kernel_launch(void* const* d_in, const int* in_sizes, int n_in,
                              void* d_out, int out_size, void* d_ws, size_t ws_size,
                              hipStream_t stream) {
    const float* g_feats = (const float*)d_in[0];
    const int* edge_src = (const int*)d_in[1];
    const int* edge_dst = (const int*)d_in[2];
    const float* W_in = (const float*)d_in[3];
    const float* b_in = (const float*)d_in[4];
    const float* W1_src = (const float*)d_in[5];
    const float* b1_src = (const float*)d_in[6];
    const float* W1_dst = (const float*)d_in[7];
    const float* b1_dst = (const float*)d_in[8];
    const float* attn1 = (const float*)d_in[9];
    const float* W2_src = (const float*)d_in[10];
    const float* b2_src = (const float*)d_in[11];
    const float* W2_dst = (const float*)d_in[12];
    const float* b2_dst = (const float*)d_in[13];
    const float* attn2 = (const float*)d_in[14];
    const float* Wh1 = (const float*)d_in[15];
    const float* bh1 = (const float*)d_in[16];
    const float* Wh2 = (const float*)d_in[17];
    const float* bh2 = (const float*)d_in[18];

    // workspace layout
    float* x = (float*)d_ws;                      // N*32
    float* fs = x + (size_t)N_NODES * 32;         // N*128
    float* fd = fs + (size_t)N_NODES * 128;       // N*128
    float* partial = fd + (size_t)N_NODES * 128;  // 256*32
    int* deg = (int*)(partial + 256 * 32);        // N
    int* row = deg + N_NODES;                     // N+1
    int* cursor = row + N_NODES + 1;              // N
    int* adj = cursor + N_NODES;                  // E (src values, CSR order)
    int* bsums = adj + N_EDGES;                   // NB

    const int EB = (N_EDGES + 255) / 256;
    const int NB = (N_NODES + 255) / 256;  // 196

    hipMemsetAsync(deg, 0, N_NODES * sizeof(int), stream);
    k_hist<<<EB, 256, 0, stream>>>(edge_dst, deg);
    k_scan_block<<<NB, 256, 0, stream>>>(deg, row, bsums);
    k_scan_sums<<<1, 256, 0, stream>>>(bsums, NB);
    k_scan_add<<<NB, 256, 0, stream>>>(row, cursor, bsums);
    k_scatter<<<EB, 256, 0, stream>>>(edge_dst, edge_src, cursor, adj);

    k_embed<<<(N_NODES * 32 + 255) / 256, 256, 0, stream>>>(g_feats, W_in, b_in, x);

    // layer 1
    k_proj<<<(N_NODES * 128 + 255) / 256, 256, 0, stream>>>(x, W1_src, b1_src, W1_dst,
                                                            b1_dst, fs, fd);
    k_gather<<<(N_NODES + 3) / 4, 256, 0, stream>>>(fs, fd, attn1, row, adj, x, 1);

    // layer 2
    k_proj<<<(N_NODES * 128 + 255) / 256, 256, 0, stream>>>(x, W2_src, b2_src, W2_dst,
                                                            b2_dst, fs, fd);
    k_gather<<<(N_NODES + 3) / 4, 256, 0, stream>>>(fs, fd, attn2, row, adj, x, 0);

    k_reduce<<<256, 256, 0, stream>>>(x, partial);
    k_final<<<1, 256, 0, stream>>>(partial, Wh1, bh1, Wh2, bh2, (float*)d_out);
}